// Round 3
// baseline (93.478 us; speedup 1.0000x reference)
//
#include <hip/hip_runtime.h>

typedef __attribute__((ext_vector_type(8))) __bf16 bf16x8;
typedef __attribute__((ext_vector_type(4))) float f32x4;

#define NB 8
#define NN 2048
#define NF 256
#define NU 256

static __device__ __forceinline__ unsigned short f2bf(float f) {
    union { float f; unsigned u; } a; a.f = f;
    unsigned r = a.u + 0x7FFFu + ((a.u >> 16) & 1u);   // RNE, no NaN inputs
    return (unsigned short)(r >> 16);
}

// ---------------- kernel 0: W -> MFMA B-fragment layout (bf16) ---------------
// WTf[z][kc][ub][lane][e] = W_z[kc*32 + (lane>>4)*8 + e][ub*16 + (lane&15)]
__global__ __launch_bounds__(256) void wfrag_kernel(
    const float* __restrict__ Wm, const float* __restrict__ Wu,
    unsigned short* __restrict__ WTf) {
    int idx = blockIdx.x * 256 + threadIdx.x;   // 16384 total
    int l  = idx & 63;
    int ub = (idx >> 6) & 15;
    int kc = (idx >> 10) & 7;
    int z  = idx >> 13;
    const float* W = z ? Wu : Wm;
    int u  = ub * 16 + (l & 15);
    int k0 = kc * 32 + (l >> 4) * 8;
    unsigned short p[8];
#pragma unroll
    for (int e = 0; e < 8; ++e) p[e] = f2bf(W[(k0 + e) * NU + u]);
    uint4 v;
    v.x = (unsigned)p[0] | ((unsigned)p[1] << 16);
    v.y = (unsigned)p[2] | ((unsigned)p[3] << 16);
    v.z = (unsigned)p[4] | ((unsigned)p[5] << 16);
    v.w = (unsigned)p[6] | ((unsigned)p[7] << 16);
    *(uint4*)(WTf + (size_t)idx * 8) = v;
}

// ---------------- kernel 1: h = bf16(x @ W_msg), stored in B-frag order ------
// Hf[b][ib][ub][lane][e] = h[b][ib*32 + (lane>>4)*8 + e][ub*16 + (lane&15)]
__global__ __launch_bounds__(256) void h_kernel(
    const float* __restrict__ x, const unsigned short* __restrict__ WTf,
    unsigned short* __restrict__ Hf) {
    int t = threadIdx.x;
    int w = t >> 6, l = t & 63;
    int l15 = l & 15, lh = l >> 4;
    int m0 = blockIdx.x * 64 + w * 16;
    const f32x4 fz = {0.f, 0.f, 0.f, 0.f};
    f32x4 acc[16];
#pragma unroll
    for (int i = 0; i < 16; ++i) acc[i] = fz;
    const float* xrow = x + (size_t)(m0 + l15) * NF;
#pragma unroll
    for (int kc = 0; kc < 8; ++kc) {
        int k0 = kc * 32 + lh * 8;
        float4 xa = *(const float4*)(xrow + k0);
        float4 xb = *(const float4*)(xrow + k0 + 4);
        union { unsigned short s[8]; bf16x8 v; } af;
        af.s[0] = f2bf(xa.x); af.s[1] = f2bf(xa.y);
        af.s[2] = f2bf(xa.z); af.s[3] = f2bf(xa.w);
        af.s[4] = f2bf(xb.x); af.s[5] = f2bf(xb.y);
        af.s[6] = f2bf(xb.z); af.s[7] = f2bf(xb.w);
#pragma unroll
        for (int ub = 0; ub < 16; ++ub) {
            union { uint4 q; bf16x8 v; } bf;
            bf.q = *(const uint4*)(WTf + (size_t)(kc * 1024 + ub * 64 + l) * 8);
            acc[ub] = __builtin_amdgcn_mfma_f32_16x16x32_bf16(af.v, bf.v, acc[ub], 0, 0, 0);
        }
    }
    int bb = m0 >> 11;            // batch
    int n0 = m0 & (NN - 1);
    int ib = n0 >> 5;
    int kl = ((n0 & 31) >> 3) + (lh >> 1);
    int e0 = (lh & 1) * 4;
#pragma unroll
    for (int ub = 0; ub < 16; ++ub) {
        unsigned short p[4];
#pragma unroll
        for (int r = 0; r < 4; ++r) p[r] = f2bf(acc[ub][r]);
        size_t off = ((size_t)((bb * 64 + ib) * 16 + ub)) * 512 + (size_t)(kl * 16 + l15) * 8 + e0;
        uint2 v;
        v.x = (unsigned)p[0] | ((unsigned)p[1] << 16);
        v.y = (unsigned)p[2] | ((unsigned)p[3] << 16);
        *(uint2*)(Hf + off) = v;
    }
}

// ---------------- kernel 2: msg GEMM + mean + fused upd GEMM + relu ----------
// 512 blocks x 256 thr (4 waves: wj in {0,1}, wu in {0,1}); block owns 32 j-rows.
// NO LDS staging, NO barriers in the K-loop: adj^T A-fragments are loaded
// directly from global (transpose is free in the fragment lane mapping;
// j = contiguous dim -> each 64B line fully used). adj 2-chunk register ring,
// Hf 1-chunk-ahead prefetch. Degree accumulated in the same registers.
__global__ __launch_bounds__(256) void msg_kernel(
    const int* __restrict__ adj, const unsigned short* __restrict__ Hf,
    const float* __restrict__ x, const unsigned short* __restrict__ WTf,
    const float* __restrict__ bias, float* __restrict__ out) {
    __shared__ float rdeg[32];

    int blk = blockIdx.x;
    int b = blk & 7, jt = blk >> 3;   // blk%8 = batch -> XCD-pinned Hf/L2 reuse
    int j0 = jt * 32;
    int t = threadIdx.x;
    int w = t >> 6, l = t & 63;
    int wj = w & 1, wu = w >> 1;
    int l15 = l & 15, lh = l >> 4;

    const f32x4 fz = {0.f, 0.f, 0.f, 0.f};
    f32x4 acc[8];
#pragma unroll
    for (int c = 0; c < 8; ++c) acc[c] = fz;

    int dsum = 0;
    // per-lane adj column base: row i = lh*8, col j = j0 + wj*16 + l15
    const int* adjcol = adj + (size_t)b * NN * NN + (size_t)(lh * 8) * NN
                        + (j0 + wj * 16 + l15);
    const unsigned short* hbase = Hf + (size_t)(b * 64 * 16 + wu * 8) * 512 + (size_t)l * 8;

    int aA[8], aB[8];
    uint4 hA[8], hB[8];

    auto LOADA = [&](int* a, int c) {
        const int* p = adjcol + (size_t)c * 32 * NN;
#pragma unroll
        for (int e = 0; e < 8; ++e) a[e] = p[(size_t)e * NN];
    };
    auto LOADH = [&](uint4* h, int c) {
        const uint4* p = (const uint4*)(hbase + (size_t)c * 16 * 512);
#pragma unroll
        for (int ub = 0; ub < 8; ++ub) h[ub] = p[ub * 64];
    };
    auto PACKMM = [&](const int* a, const uint4* h) {
        union { unsigned u[4]; bf16x8 v; } pk;
#pragma unroll
        for (int k = 0; k < 4; ++k) {
            if (wu == 0) dsum += a[2 * k] + a[2 * k + 1];
            // adj in {0,1}: packed bf16 pair = (a0 | a1<<16) * 0x3F80
            pk.u[k] = ((unsigned)(a[2 * k] | (a[2 * k + 1] << 16))) * 0x3F80u;
        }
#pragma unroll
        for (int ub = 0; ub < 8; ++ub) {
            union { uint4 q; bf16x8 v; } bf;
            bf.q = h[ub];
            acc[ub] = __builtin_amdgcn_mfma_f32_16x16x32_bf16(pk.v, bf.v, acc[ub], 0, 0, 0);
        }
    };

    // prologue
    LOADA(aA, 0); LOADA(aB, 1); LOADH(hA, 0);

#pragma unroll 1
    for (int c = 0; c < 64; c += 2) {
        int c2 = (c + 2 < 64) ? c + 2 : 63;   // clamped redundant tail reloads
        int c3 = (c + 3 < 64) ? c + 3 : 63;
        LOADH(hB, c + 1);
        PACKMM(aA, hA);          // consumes aA (chunk c), hA
        LOADA(aA, c2);           // refill ~2 chunks ahead
        LOADH(hA, c2);
        PACKMM(aB, hB);          // consumes aB (chunk c+1), hB
        LOADA(aB, c3);
    }

    // degree: dsum held per-lane by wu==0 waves; reduce across lh groups
    dsum += __shfl_xor(dsum, 16, 64);
    dsum += __shfl_xor(dsum, 32, 64);
    if (wu == 0) rdeg[wj * 16 + l15] = dsum > 0 ? 1.0f / (float)dsum : 0.0f;
    __syncthreads();

    // scale msg accumulator by 1/deg (TF segment-mean: deg==0 -> 0)
#pragma unroll
    for (int r = 0; r < 4; ++r) {
        float sc = rdeg[wj * 16 + lh * 4 + r];
#pragma unroll
        for (int ub = 0; ub < 8; ++ub) acc[ub][r] *= sc;
    }

    // fused upd GEMM: acc += bf16(x_rows) @ W_upd
    const float* xrow = x + ((size_t)b * NN + j0 + wj * 16 + l15) * NF;
#pragma unroll
    for (int kc = 0; kc < 8; ++kc) {
        int k0 = kc * 32 + lh * 8;
        float4 xa = *(const float4*)(xrow + k0);
        float4 xc = *(const float4*)(xrow + k0 + 4);
        union { unsigned short sh[8]; bf16x8 v; } af;
        af.sh[0] = f2bf(xa.x); af.sh[1] = f2bf(xa.y);
        af.sh[2] = f2bf(xa.z); af.sh[3] = f2bf(xa.w);
        af.sh[4] = f2bf(xc.x); af.sh[5] = f2bf(xc.y);
        af.sh[6] = f2bf(xc.z); af.sh[7] = f2bf(xc.w);
#pragma unroll
        for (int ub = 0; ub < 8; ++ub) {
            int ubg = wu * 8 + ub;
            union { uint4 q; bf16x8 v; } bf;
            bf.q = *(const uint4*)(WTf + (size_t)(8192 + kc * 1024 + ubg * 64 + l) * 8);
            acc[ub] = __builtin_amdgcn_mfma_f32_16x16x32_bf16(af.v, bf.v, acc[ub], 0, 0, 0);
        }
    }

    // epilogue: + bias, relu, store
    float* ob = out + ((size_t)b * NN + j0 + wj * 16) * NU + wu * 128;
#pragma unroll
    for (int ub = 0; ub < 8; ++ub) {
        int u = wu * 128 + ub * 16 + l15;
        float bv = bias[u];
#pragma unroll
        for (int r = 0; r < 4; ++r) {
            float v = acc[ub][r] + bv;
            ob[(size_t)(lh * 4 + r) * NU + ub * 16 + l15] = fmaxf(v, 0.f);
        }
    }
}

extern "C" void kernel_launch(void* const* d_in, const int* in_sizes, int n_in,
                              void* d_out, int out_size, void* d_ws, size_t ws_size,
                              hipStream_t stream) {
    const float* x    = (const float*)d_in[0];
    const int*   adj  = (const int*)d_in[1];
    const float* Wm   = (const float*)d_in[2];
    const float* Wu   = (const float*)d_in[3];
    const float* bias = (const float*)d_in[4];
    float* out = (float*)d_out;

    unsigned short* WTf = (unsigned short*)d_ws;                      // 256 KiB
    unsigned short* Hf  = (unsigned short*)((char*)d_ws + (1 << 18)); // 8 MiB

    wfrag_kernel<<<64, 256, 0, stream>>>(Wm, Wu, WTf);
    h_kernel<<<256, 256, 0, stream>>>(x, WTf, Hf);
    msg_kernel<<<512, 256, 0, stream>>>(adj, Hf, x, WTf, bias, out);
}

// Round 4
// 72.718 us; speedup vs baseline: 1.2855x; 1.2855x over previous
//
#include <hip/hip_runtime.h>

typedef __attribute__((ext_vector_type(8))) __bf16 bf16x8;
typedef __attribute__((ext_vector_type(4))) float f32x4;

#define NB 8
#define NN 2048
#define NF 256
#define NU 256

static __device__ __forceinline__ unsigned short f2bf(float f) {
    union { float f; unsigned u; } a; a.f = f;
    unsigned r = a.u + 0x7FFFu + ((a.u >> 16) & 1u);   // RNE, no NaN inputs
    return (unsigned short)(r >> 16);
}

// barrier WITHOUT vmcnt drain: LDS ops flushed (lgkmcnt), global loads stay in flight
static __device__ __forceinline__ void barrier_nodrain() {
    asm volatile("s_waitcnt lgkmcnt(0)" ::: "memory");
    __builtin_amdgcn_s_barrier();
    asm volatile("" ::: "memory");
}

// ---------------- kernel 0: W -> MFMA B-fragment layout (bf16) ---------------
// WTf[z][kc][ub][lane][e] = W_z[kc*32 + (lane>>4)*8 + e][ub*16 + (lane&15)]
__global__ __launch_bounds__(256) void wfrag_kernel(
    const float* __restrict__ Wm, const float* __restrict__ Wu,
    unsigned short* __restrict__ WTf) {
    int idx = blockIdx.x * 256 + threadIdx.x;   // 16384 total
    int l  = idx & 63;
    int ub = (idx >> 6) & 15;
    int kc = (idx >> 10) & 7;
    int z  = idx >> 13;
    const float* W = z ? Wu : Wm;
    int u  = ub * 16 + (l & 15);
    int k0 = kc * 32 + (l >> 4) * 8;
    unsigned short p[8];
#pragma unroll
    for (int e = 0; e < 8; ++e) p[e] = f2bf(W[(k0 + e) * NU + u]);
    uint4 v;
    v.x = (unsigned)p[0] | ((unsigned)p[1] << 16);
    v.y = (unsigned)p[2] | ((unsigned)p[3] << 16);
    v.z = (unsigned)p[4] | ((unsigned)p[5] << 16);
    v.w = (unsigned)p[6] | ((unsigned)p[7] << 16);
    *(uint4*)(WTf + (size_t)idx * 8) = v;
}

// ---------------- kernel 1: h = bf16(x @ W_msg), stored in B-frag order ------
// Hf[b][ib][ub][lane][e] = h[b][ib*32 + (lane>>4)*8 + e][ub*16 + (lane&15)]
__global__ __launch_bounds__(256) void h_kernel(
    const float* __restrict__ x, const unsigned short* __restrict__ WTf,
    unsigned short* __restrict__ Hf) {
    int t = threadIdx.x;
    int w = t >> 6, l = t & 63;
    int l15 = l & 15, lh = l >> 4;
    int m0 = blockIdx.x * 64 + w * 16;
    const f32x4 fz = {0.f, 0.f, 0.f, 0.f};
    f32x4 acc[16];
#pragma unroll
    for (int i = 0; i < 16; ++i) acc[i] = fz;
    const float* xrow = x + (size_t)(m0 + l15) * NF;
#pragma unroll
    for (int kc = 0; kc < 8; ++kc) {
        int k0 = kc * 32 + lh * 8;
        float4 xa = *(const float4*)(xrow + k0);
        float4 xb = *(const float4*)(xrow + k0 + 4);
        union { unsigned short s[8]; bf16x8 v; } af;
        af.s[0] = f2bf(xa.x); af.s[1] = f2bf(xa.y);
        af.s[2] = f2bf(xa.z); af.s[3] = f2bf(xa.w);
        af.s[4] = f2bf(xb.x); af.s[5] = f2bf(xb.y);
        af.s[6] = f2bf(xb.z); af.s[7] = f2bf(xb.w);
#pragma unroll
        for (int ub = 0; ub < 16; ++ub) {
            union { uint4 q; bf16x8 v; } bf;
            bf.q = *(const uint4*)(WTf + (size_t)(kc * 1024 + ub * 64 + l) * 8);
            acc[ub] = __builtin_amdgcn_mfma_f32_16x16x32_bf16(af.v, bf.v, acc[ub], 0, 0, 0);
        }
    }
    int bb = m0 >> 11;            // batch
    int n0 = m0 & (NN - 1);
    int ib = n0 >> 5;
    int kl = ((n0 & 31) >> 3) + (lh >> 1);
    int e0 = (lh & 1) * 4;
#pragma unroll
    for (int ub = 0; ub < 16; ++ub) {
        unsigned short p[4];
#pragma unroll
        for (int r = 0; r < 4; ++r) p[r] = f2bf(acc[ub][r]);
        size_t off = ((size_t)((bb * 64 + ib) * 16 + ub)) * 512 + (size_t)(kl * 16 + l15) * 8 + e0;
        uint2 v;
        v.x = (unsigned)p[0] | ((unsigned)p[1] << 16);
        v.y = (unsigned)p[2] | ((unsigned)p[3] << 16);
        *(uint2*)(Hf + off) = v;
    }
}

// ---------------- kernel 2: msg GEMM + mean + fused upd GEMM + relu ----------
// 512 blocks (2/CU) x 256 thr (4 waves, wave = j-tile 32 x u-tile 64).
// adj staged to LDS (int -> bf16, transposed, 16B-XOR-swizzled), double-buffered,
// 1 no-vmcnt-drain barrier per chunk. adj register ring depth 4 (~1800cy lead),
// Hf register ring depth 2. Small VGPR footprint so the compiler keeps the rings.
__global__ __launch_bounds__(256) void msg_kernel(
    const int* __restrict__ adj, const unsigned short* __restrict__ Hf,
    const float* __restrict__ x, const unsigned short* __restrict__ WTf,
    const float* __restrict__ bias, float* __restrict__ out) {
    __shared__ unsigned short Abuf[2][1024];   // 2 x 2KB: [j 0..31][i 0..31] bf16, swizzled
    __shared__ int degs[256];
    __shared__ float rdeg[32];

    int blk = blockIdx.x;
    int b = blk & 7, jt = blk >> 3;   // blk%8 = batch -> XCD-pinned Hf/L2 reuse
    int j0 = jt * 32;
    int t = threadIdx.x;
    int w = t >> 6, l = t & 63;       // w = wave id = u-quarter
    int l15 = l & 15, lh = l >> 4;
    int jj = t & 31, ig = t >> 5;     // stage mapping: col j0+jj, row group ig (8 groups x 4 rows)

    const f32x4 fz = {0.f, 0.f, 0.f, 0.f};
    f32x4 acc[2][4];
#pragma unroll
    for (int a = 0; a < 2; ++a)
#pragma unroll
        for (int c = 0; c < 4; ++c) acc[a][c] = fz;

    const int* adjst = adj + (size_t)b * NN * NN + (size_t)(ig * 4) * NN + (j0 + jj);
    const unsigned short* hbase = Hf + (size_t)(b * 64 * 16 + w * 4) * 512 + (size_t)l * 8;

    int dsum = 0;
    int r0[4], r1[4], r2[4], r3[4], rz[4];   // adj ring (named: rule #20)
    uint4 hA[4], hB[4];                      // Hf ring (2 chunks)

    auto LOADINT = [&](int* r, int c) {
#pragma unroll
        for (int e = 0; e < 4; ++e) r[e] = adjst[((size_t)c * 32 + e) * NN];
    };
    auto LOADH = [&](uint4* h, int c) {
        const uint4* p = (const uint4*)(hbase + (size_t)c * 16 * 512);
#pragma unroll
        for (int ub = 0; ub < 4; ++ub) h[ub] = p[ub * 64];
    };
    // stage: bf16 pair pack + swizzled transpose write; one ds_write_b64/thread
    // byte(j,i) = j*64 + ((i*2) ^ ((j&3)<<4))  [XOR bits 4..5 only: b64/b128-safe]
    auto PACKWRITE = [&](int buf, const int* r, bool valid) {
        if (valid) dsum += r[0] + r[1] + r[2] + r[3];
        uint2 v;
        v.x = ((unsigned)(r[0] | (r[1] << 16))) * 0x3F80u;
        v.y = ((unsigned)(r[2] | (r[3] << 16))) * 0x3F80u;
        *(uint2*)((char*)(&Abuf[buf][0]) + jj * 64 + ((ig * 8) ^ ((jj & 3) << 4))) = v;
    };
    auto COMPUTE = [&](int buf, const uint4* h) {
#pragma unroll
        for (int jf = 0; jf < 2; ++jf) {
            int j = jf * 16 + l15;
            bf16x8 af = *(const bf16x8*)((const char*)(&Abuf[buf][0]) +
                                         j * 64 + ((lh * 16) ^ ((j & 3) << 4)));
#pragma unroll
            for (int ub = 0; ub < 4; ++ub) {
                union { uint4 q; bf16x8 v; } bf;
                bf.q = h[ub];
                acc[jf][ub] = __builtin_amdgcn_mfma_f32_16x16x32_bf16(af, bf.v, acc[jf][ub], 0, 0, 0);
            }
        }
    };

    // prologue: chunk0 ints + stage; ring holds chunks 1..4; Hf chunks 0,1 in flight
    LOADINT(rz, 0);
    LOADINT(r0, 1); LOADINT(r1, 2); LOADINT(r2, 3); LOADINT(r3, 4);
    LOADH(hA, 0); LOADH(hB, 1);
    PACKWRITE(0, rz, true);
    barrier_nodrain();

    // 16 iterations x 4 chunks; phase p: compute buf(p&1) chunk p, write buf(p^1) chunk p+1
#pragma unroll 1
    for (int c4 = 0; c4 < 64; c4 += 4) {
        PACKWRITE(1, r0, true);
        LOADINT(r0, (c4 + 5 < 64) ? c4 + 5 : 63);
        COMPUTE(0, hA);
        LOADH(hA, (c4 + 2 < 64) ? c4 + 2 : 63);
        barrier_nodrain();

        PACKWRITE(0, r1, true);
        LOADINT(r1, (c4 + 6 < 64) ? c4 + 6 : 63);
        COMPUTE(1, hB);
        LOADH(hB, (c4 + 3 < 64) ? c4 + 3 : 63);
        barrier_nodrain();

        PACKWRITE(1, r2, true);
        LOADINT(r2, (c4 + 7 < 64) ? c4 + 7 : 63);
        COMPUTE(0, hA);
        LOADH(hA, (c4 + 4 < 64) ? c4 + 4 : 63);
        barrier_nodrain();

        PACKWRITE(0, r3, c4 + 4 < 64);     // last iter: chunk 64 doesn't exist
        LOADINT(r3, (c4 + 8 < 64) ? c4 + 8 : 63);
        COMPUTE(1, hB);
        LOADH(hB, (c4 + 5 < 64) ? c4 + 5 : 63);
        barrier_nodrain();
    }

    // degree reduce: deg[j] = sum over 8 ig groups
    degs[t] = dsum;
    barrier_nodrain();
    if (t < 32) {
        int d = 0;
#pragma unroll
        for (int g = 0; g < 8; ++g) d += degs[t + 32 * g];
        rdeg[t] = d > 0 ? 1.0f / (float)d : 0.0f;
    }
    barrier_nodrain();

    // scale msg accumulator by 1/deg (TF segment-mean: deg==0 -> 0)
#pragma unroll
    for (int jf = 0; jf < 2; ++jf)
#pragma unroll
        for (int rr = 0; rr < 4; ++rr) {
            float sc = rdeg[jf * 16 + lh * 4 + rr];
#pragma unroll
            for (int ub = 0; ub < 4; ++ub) acc[jf][ub][rr] *= sc;
        }

    // fused upd GEMM: acc += bf16(x_rows) @ W_upd
    const float* xb = x + ((size_t)b * NN + j0) * NF;
#pragma unroll
    for (int kc = 0; kc < 8; ++kc) {
        int k0 = kc * 32 + lh * 8;
        bf16x8 xf[2];
#pragma unroll
        for (int jf = 0; jf < 2; ++jf) {
            const float* xr = xb + (size_t)(jf * 16 + l15) * NF + k0;
            float4 xa = *(const float4*)xr;
            float4 xc = *(const float4*)(xr + 4);
            union { unsigned short sh[8]; bf16x8 v; } af;
            af.sh[0] = f2bf(xa.x); af.sh[1] = f2bf(xa.y);
            af.sh[2] = f2bf(xa.z); af.sh[3] = f2bf(xa.w);
            af.sh[4] = f2bf(xc.x); af.sh[5] = f2bf(xc.y);
            af.sh[6] = f2bf(xc.z); af.sh[7] = f2bf(xc.w);
            xf[jf] = af.v;
        }
#pragma unroll
        for (int ub = 0; ub < 4; ++ub) {
            int ubg = w * 4 + ub;
            union { uint4 q; bf16x8 v; } bf;
            bf.q = *(const uint4*)(WTf + (size_t)(8192 + kc * 1024 + ubg * 64 + l) * 8);
            acc[0][ub] = __builtin_amdgcn_mfma_f32_16x16x32_bf16(xf[0], bf.v, acc[0][ub], 0, 0, 0);
            acc[1][ub] = __builtin_amdgcn_mfma_f32_16x16x32_bf16(xf[1], bf.v, acc[1][ub], 0, 0, 0);
        }
    }

    // epilogue: + bias, relu, store
    float* ob = out + ((size_t)b * NN + j0) * NU;
#pragma unroll
    for (int jf = 0; jf < 2; ++jf)
#pragma unroll
        for (int ub = 0; ub < 4; ++ub) {
            int u = (w * 4 + ub) * 16 + l15;
            float bv = bias[u];
#pragma unroll
            for (int rr = 0; rr < 4; ++rr) {
                float v = acc[jf][ub][rr] + bv;
                ob[(size_t)(jf * 16 + lh * 4 + rr) * NU + u] = fmaxf(v, 0.f);
            }
        }
}

extern "C" void kernel_launch(void* const* d_in, const int* in_sizes, int n_in,
                              void* d_out, int out_size, void* d_ws, size_t ws_size,
                              hipStream_t stream) {
    const float* x    = (const float*)d_in[0];
    const int*   adj  = (const int*)d_in[1];
    const float* Wm   = (const float*)d_in[2];
    const float* Wu   = (const float*)d_in[3];
    const float* bias = (const float*)d_in[4];
    float* out = (float*)d_out;

    unsigned short* WTf = (unsigned short*)d_ws;                      // 256 KiB
    unsigned short* Hf  = (unsigned short*)((char*)d_ws + (1 << 18)); // 8 MiB

    wfrag_kernel<<<64, 256, 0, stream>>>(Wm, Wu, WTf);
    h_kernel<<<256, 256, 0, stream>>>(x, WTf, Hf);
    msg_kernel<<<512, 256, 0, stream>>>(adj, Hf, x, WTf, bias, out);
}